// Round 7
// baseline (470.008 us; speedup 1.0000x reference)
//
#include <hip/hip_runtime.h>
#include <hip/hip_bf16.h>
#include <math.h>

#define BB 64
#define NN 320
#define NT 256
#define NV 32
#define NA 32
#define HIDD 512
#define NHEAD 8
#define FD 64

#define LDK 40    // GEMM LDS k-stride (bf16 units)

typedef __attribute__((ext_vector_type(8))) short bf16x8;
typedef __attribute__((ext_vector_type(4))) float floatx4;

__device__ __forceinline__ void split1(float v, unsigned short& h, unsigned short& l) {
    unsigned u = __float_as_uint(v);
    unsigned hu = u & 0xFFFF0000u;
    float lf = v - __uint_as_float(hu);
    h = (unsigned short)(hu >> 16);
    l = (unsigned short)(__float_as_uint(lf) >> 16);
}
__device__ __forceinline__ unsigned pack2(unsigned short a, unsigned short b) {
    return (unsigned)a | ((unsigned)b << 16);
}

// ---------------------------------------------------------------------------
// Split-bf16 MFMA GEMM (unchanged from R6 — verified). C[M,512]=A[M,K]@B[K,512].
// b_mode 0: fp32 x epilogue w/ node remap. b_mode 1: Ht split-bf16 epilogue in
// MFMA B-fragment layout Ht[slab][ks][nt][lane=(f&15)|(((j>>3)&3)<<4)][e=j&7].
// ---------------------------------------------------------------------------
__global__ __launch_bounds__(256) void gemm_mfma(
    const float* __restrict__ A, const float* __restrict__ Bsrc,
    float* __restrict__ C, unsigned short* __restrict__ Hthi,
    unsigned short* __restrict__ Htlo, int M, int K, int b_mode, int rpb, int noff)
{
    __shared__ unsigned short Ah[128 * LDK];
    __shared__ unsigned short Al[128 * LDK];
    __shared__ unsigned short Bh[128 * LDK];
    __shared__ unsigned short Bl[128 * LDK];

    const int tid  = threadIdx.x;
    const int lane = tid & 63;
    const int w    = tid >> 6;
    const int rw   = w >> 1, cw = w & 1;
    const int m0   = blockIdx.x * 128;
    const int n0   = blockIdx.y * 128;

    floatx4 acc[4][4];
#pragma unroll
    for (int s = 0; s < 4; s++)
#pragma unroll
        for (int t = 0; t < 4; t++) acc[s][t] = (floatx4)0.f;

    const int arow = tid >> 1;
    const int akh  = (tid & 1) * 16;
    const int bc   = tid & 127;
    const int bkh  = (tid >> 7) * 16;
    const int bhead = (n0 + bc) >> 6;
    const int bf    = (n0 + bc) & 63;

    const int afrag0 = (rw * 64 + (lane & 15)) * LDK + (lane >> 4) * 8;
    const int bfrag0 = (cw * 64 + (lane & 15)) * LDK + (lane >> 4) * 8;

    for (int k0 = 0; k0 < K; k0 += 32) {
        __syncthreads();
        {
            const float* ga = A + (size_t)(m0 + arow) * K + k0 + akh;
            const int la = arow * LDK + akh;
            if (k0 + 32 <= K) {
#pragma unroll
                for (int u = 0; u < 4; u++) {
                    float4 v = *(const float4*)(ga + 4 * u);
                    unsigned short h0,h1,h2,h3,l0,l1,l2,l3;
                    split1(v.x,h0,l0); split1(v.y,h1,l1);
                    split1(v.z,h2,l2); split1(v.w,h3,l3);
                    *(uint2*)&Ah[la + 4*u] = make_uint2(pack2(h0,h1), pack2(h2,h3));
                    *(uint2*)&Al[la + 4*u] = make_uint2(pack2(l0,l1), pack2(l2,l3));
                }
            } else {
#pragma unroll
                for (int u = 0; u < 16; u++) {
                    float v = (k0 + akh + u < K) ? ga[u] : 0.f;
                    unsigned short h, l; split1(v, h, l);
                    Ah[la + u] = h; Al[la + u] = l;
                }
            }
        }
        {
            unsigned short hb[16], lb[16];
#pragma unroll
            for (int u = 0; u < 16; u++) {
                int k = k0 + bkh + u;
                float v;
                if (k < K) {
                    size_t gi = b_mode
                        ? (size_t)bhead * (512 * 64) + (size_t)k * 64 + bf
                        : (size_t)k * 512 + n0 + bc;
                    v = Bsrc[gi];
                } else v = 0.f;
                split1(v, hb[u], lb[u]);
            }
            const int lb0 = bc * LDK + bkh;
#pragma unroll
            for (int u = 0; u < 4; u++) {
                *(uint2*)&Bh[lb0 + 4*u] = make_uint2(pack2(hb[4*u],hb[4*u+1]), pack2(hb[4*u+2],hb[4*u+3]));
                *(uint2*)&Bl[lb0 + 4*u] = make_uint2(pack2(lb[4*u],lb[4*u+1]), pack2(lb[4*u+2],lb[4*u+3]));
            }
        }
        __syncthreads();

        bf16x8 ah[4], al[4], bh[4], bl[4];
#pragma unroll
        for (int s = 0; s < 4; s++) {
            ah[s] = *(const bf16x8*)&Ah[afrag0 + s * 16 * LDK];
            al[s] = *(const bf16x8*)&Al[afrag0 + s * 16 * LDK];
        }
#pragma unroll
        for (int t = 0; t < 4; t++) {
            bh[t] = *(const bf16x8*)&Bh[bfrag0 + t * 16 * LDK];
            bl[t] = *(const bf16x8*)&Bl[bfrag0 + t * 16 * LDK];
        }
#pragma unroll
        for (int s = 0; s < 4; s++)
#pragma unroll
            for (int t = 0; t < 4; t++) {
                acc[s][t] = __builtin_amdgcn_mfma_f32_16x16x32_bf16(ah[s], bh[t], acc[s][t], 0, 0, 0);
                acc[s][t] = __builtin_amdgcn_mfma_f32_16x16x32_bf16(ah[s], bl[t], acc[s][t], 0, 0, 0);
                acc[s][t] = __builtin_amdgcn_mfma_f32_16x16x32_bf16(al[s], bh[t], acc[s][t], 0, 0, 0);
            }
    }

    if (b_mode == 0) {
#pragma unroll
        for (int s = 0; s < 4; s++) {
            const int gr0 = m0 + rw * 64 + s * 16 + (lane >> 4) * 4;
#pragma unroll
            for (int r = 0; r < 4; r++) {
                const unsigned grow = gr0 + r;
                const unsigned b = grow / (unsigned)rpb;
                const unsigned rr = grow - b * rpb;
                float* crow = C + ((size_t)b * NN + noff + rr) * HIDD;
#pragma unroll
                for (int t = 0; t < 4; t++) {
                    crow[n0 + cw * 64 + t * 16 + (lane & 15)] = acc[s][t][r];
                }
            }
        }
    } else {
        const int hd = (n0 + cw * 64) >> 6;
        const int fq = lane & 15;
#pragma unroll
        for (int s = 0; s < 4; s++) {
            const int m_s = m0 + rw * 64 + s * 16 + (lane >> 4) * 4;
            const unsigned b = (unsigned)m_s / 320u;
            const int jb = m_s - b * 320;
            const int ks = jb >> 5;
            const int jg2 = (jb >> 3) & 3;
            const int eb = jb & 7;
            const size_t slab = (size_t)b * 8 + hd;
#pragma unroll
            for (int t = 0; t < 4; t++) {
                unsigned short h0,h1,h2,h3,l0,l1,l2,l3;
                split1(acc[s][t][0],h0,l0); split1(acc[s][t][1],h1,l1);
                split1(acc[s][t][2],h2,l2); split1(acc[s][t][3],h3,l3);
                const size_t base = (((slab * 10 + ks) * 4 + t) * 512
                                     + (size_t)(fq | (jg2 << 4)) * 8) + eb;
                *(uint2*)&Hthi[base] = make_uint2(pack2(h0,h1), pack2(h2,h3));
                *(uint2*)&Htlo[base] = make_uint2(pack2(l0,l1), pack2(l2,l3));
            }
        }
    }
}

// ---------------------------------------------------------------------------
// MFMA GAT attention. Block = (b, head, i-half of 160 rows): grid 1024,
// 512 threads (8 waves), launch_bounds(512,6) -> 3 blocks/CU, 24 waves/CU.
// Pre-pass: fj all 320 nodes (+fi own 160) from Ht frags, shfl+LDS atomics.
// Per 32-j chunk: B-frags prefetched from global (frag layout), scores ->
// p=exp(s) split-bf16 into LDS A-frag layout, 3-pass MFMA PV.
// Wave w: nt=w&3, mt = (w>>2)*5 + 0..4 (acc[5]).
// ---------------------------------------------------------------------------
__global__ __launch_bounds__(512, 6) void attn_mfma(
    const unsigned short* __restrict__ Hthi, const unsigned short* __restrict__ Htlo,
    const float* __restrict__ asrc, const float* __restrict__ adst,
    const int*   __restrict__ adj,  const float* __restrict__ elog,
    float* __restrict__ xout, int apply_elu)
{
    __shared__ unsigned short Pfh[10 * 64 * 8];   // 10 KB, A-frag layout
    __shared__ unsigned short Pfl[10 * 64 * 8];   // 10 KB
    __shared__ float fjs[NN];
    __shared__ float fis[160];
    __shared__ float ls[160];

    const int blk = blockIdx.x;
    const int ih = blk & 1;             // i-half
    const int bh = blk >> 1;            // b*8 + hd
    const int hd = bh & 7, b = bh >> 3;
    const int tid = threadIdx.x, lane = tid & 63, w = tid >> 3 >> 3;  // w = tid>>6

    for (int r = tid; r < NN; r += 512) fjs[r] = 0.f;
    for (int r = tid; r < 160; r += 512) { fis[r] = 0.f; ls[r] = 0.f; }
    __syncthreads();

    // ---- pre-pass: fj for all 320 nodes; fi for own 160 ----
#pragma unroll
    for (int u = 0; u < 5; u++) {
        const int idx = u * 8 + w;            // 0..39
        const int ks = idx >> 2, nt = idx & 3;
        const int f = nt * 16 + (lane & 15);
        const float as = asrc[hd * 64 + f];
        const float ad = adst[hd * 64 + f];
        const size_t off = (((size_t)bh * 10 + ks) * 4 + nt) * 512 + (size_t)lane * 8;
        bf16x8 hh = *(const bf16x8*)&Hthi[off];
        bf16x8 hl = *(const bf16x8*)&Htlo[off];
        float hv[8];
#pragma unroll
        for (int e = 0; e < 8; e++)
            hv[e] = __uint_as_float(((unsigned)(unsigned short)hh[e]) << 16)
                  + __uint_as_float(((unsigned)(unsigned short)hl[e]) << 16);
        const bool own = (ks >= ih * 5) && (ks < ih * 5 + 5);   // wave-uniform
        float fjv[8];
#pragma unroll
        for (int e = 0; e < 8; e++) fjv[e] = hv[e] * ad;
#pragma unroll
        for (int d = 1; d < 16; d <<= 1)
#pragma unroll
            for (int e = 0; e < 8; e++) fjv[e] += __shfl_xor(fjv[e], d);
        if (own) {
            float fiv[8];
#pragma unroll
            for (int e = 0; e < 8; e++) fiv[e] = hv[e] * as;
#pragma unroll
            for (int d = 1; d < 16; d <<= 1)
#pragma unroll
                for (int e = 0; e < 8; e++) fiv[e] += __shfl_xor(fiv[e], d);
            if ((lane & 15) == 0) {
                const int jb = ks * 32 + (lane >> 4) * 8;
#pragma unroll
                for (int e = 0; e < 8; e++) {
                    atomicAdd(&fjs[jb + e], fjv[e]);
                    atomicAdd(&fis[jb + e - ih * 160], fiv[e]);
                }
            }
        } else if ((lane & 15) == 0) {
            const int jb = ks * 32 + (lane >> 4) * 8;
#pragma unroll
            for (int e = 0; e < 8; e++) atomicAdd(&fjs[jb + e], fjv[e]);
        }
    }
    __syncthreads();

    floatx4 acc[5];
#pragma unroll
    for (int q = 0; q < 5; q++) acc[q] = (floatx4)0.f;
    const int nt = w & 3;
    const int mtb = (w >> 2) * 5;

    for (int ks = 0; ks < 10; ks++) {
        if (ks) __syncthreads();   // prev chunk MFMA done before P overwrite

        // prefetch B-frags for this chunk (latency hides under score VALU)
        const size_t boff = (((size_t)bh * 10 + ks) * 4 + nt) * 512 + (size_t)lane * 8;
        const bf16x8 bhf = *(const bf16x8*)&Hthi[boff];
        const bf16x8 blf = *(const bf16x8*)&Htlo[boff];

        // score phase: 160 i x 32 j = 640 (i,jg) units over 512 threads
        for (int e2 = tid; e2 < 640; e2 += 512) {
            const int i_loc = e2 >> 2, jg = e2 & 3;
            const int j8 = ks * 32 + jg * 8;
            const float4 fj0 = *(const float4*)&fjs[j8];
            const float4 fj1 = *(const float4*)&fjs[j8 + 4];
            const float fiv = fis[i_loc];
            const size_t g = (size_t)(ih * 160 + i_loc) * NN + j8;
            const int4   a0 = *(const int4*)&adj[g];
            const int4   a1 = *(const int4*)&adj[g + 4];
            const float4 e0 = *(const float4*)&elog[g];
            const float4 e1 = *(const float4*)&elog[g + 4];
            float p[8];
            float s;
            s = fiv + fj0.x; s = fmaxf(s, 0.2f*s); s = a0.x ? (s + e0.x) : -INFINITY; p[0] = __expf(s);
            s = fiv + fj0.y; s = fmaxf(s, 0.2f*s); s = a0.y ? (s + e0.y) : -INFINITY; p[1] = __expf(s);
            s = fiv + fj0.z; s = fmaxf(s, 0.2f*s); s = a0.z ? (s + e0.z) : -INFINITY; p[2] = __expf(s);
            s = fiv + fj0.w; s = fmaxf(s, 0.2f*s); s = a0.w ? (s + e0.w) : -INFINITY; p[3] = __expf(s);
            s = fiv + fj1.x; s = fmaxf(s, 0.2f*s); s = a1.x ? (s + e1.x) : -INFINITY; p[4] = __expf(s);
            s = fiv + fj1.y; s = fmaxf(s, 0.2f*s); s = a1.y ? (s + e1.y) : -INFINITY; p[5] = __expf(s);
            s = fiv + fj1.z; s = fmaxf(s, 0.2f*s); s = a1.z ? (s + e1.z) : -INFINITY; p[6] = __expf(s);
            s = fiv + fj1.w; s = fmaxf(s, 0.2f*s); s = a1.w ? (s + e1.w) : -INFINITY; p[7] = __expf(s);
            const float lsum = ((p[0]+p[1]) + (p[2]+p[3])) + ((p[4]+p[5]) + (p[6]+p[7]));
            unsigned short ph[8], pl[8];
#pragma unroll
            for (int e = 0; e < 8; e++) split1(p[e], ph[e], pl[e]);
            const int mt = i_loc >> 4;
            const int lane_t = (i_loc & 15) | (jg << 4);
            const size_t po = ((size_t)mt * 64 + lane_t) * 8;
            *(uint4*)&Pfh[po] = make_uint4(pack2(ph[0],ph[1]), pack2(ph[2],ph[3]),
                                           pack2(ph[4],ph[5]), pack2(ph[6],ph[7]));
            *(uint4*)&Pfl[po] = make_uint4(pack2(pl[0],pl[1]), pack2(pl[2],pl[3]),
                                           pack2(pl[4],pl[5]), pack2(pl[6],pl[7]));
            atomicAdd(&ls[i_loc], lsum);
        }
        __syncthreads();

        // 3-pass MFMA PV for own 5 m-tiles
#pragma unroll
        for (int q = 0; q < 5; q++) {
            const int mt = mtb + q;
            const bf16x8 ah = *(const bf16x8*)&Pfh[((size_t)mt * 64 + lane) * 8];
            const bf16x8 al = *(const bf16x8*)&Pfl[((size_t)mt * 64 + lane) * 8];
            acc[q] = __builtin_amdgcn_mfma_f32_16x16x32_bf16(ah, bhf, acc[q], 0, 0, 0);
            acc[q] = __builtin_amdgcn_mfma_f32_16x16x32_bf16(al, bhf, acc[q], 0, 0, 0);
            acc[q] = __builtin_amdgcn_mfma_f32_16x16x32_bf16(ah, blf, acc[q], 0, 0, 0);
        }
    }
    __syncthreads();

    // ---- epilogue: D col(f)=lane&15, row(i)=(lane>>4)*4+reg ----
    const int fq = lane & 15;
#pragma unroll
    for (int q = 0; q < 5; q++) {
        const int ibl = (mtb + q) * 16 + (lane >> 4) * 4;
#pragma unroll
        for (int r = 0; r < 4; r++) {
            const float lv = ls[ibl + r];
            const float inv = (lv > 0.f) ? 1.f / lv : 0.f;   // fully-masked row -> 0
            float v = acc[q][r] * inv;
            if (apply_elu) v = (v > 0.f) ? v : __expf(v) - 1.f;
            xout[((size_t)(b * NN + ih * 160 + ibl + r)) * HIDD + hd * 64 + nt * 16 + fq] = v;
        }
    }
}

// ---------------------------------------------------------------------------
// Workspace: Ht hi + lo planes = 41,943,040 B == out bytes exactly (ws cap
// established by R2-crash/R3-pass evidence). Flow: proj -> d_out (x);
// per layer: gemm_h x->Ht(ws); attn Ht->x/final (d_out). Sequential.
// ---------------------------------------------------------------------------
extern "C" void kernel_launch(void* const* d_in, const int* in_sizes, int n_in,
                              void* d_out, int out_size, void* d_ws, size_t ws_size,
                              hipStream_t stream)
{
    (void)in_sizes; (void)n_in; (void)out_size; (void)ws_size;
    const float* text     = (const float*)d_in[0];
    const float* visual   = (const float*)d_in[1];
    const float* acoustic = (const float*)d_in[2];
    const int*   adj      = (const int*)d_in[3];
    const float* Wt       = (const float*)d_in[4];
    const float* Wv       = (const float*)d_in[5];
    const float* Wa       = (const float*)d_in[6];
    const float* Wg       = (const float*)d_in[7];
    const float* a_src    = (const float*)d_in[8];
    const float* a_dst    = (const float*)d_in[9];
    const float* elog     = (const float*)d_in[10];

    float* xbuf = (float*)d_out;
    unsigned short* Hthi = (unsigned short*)d_ws;
    unsigned short* Htlo = Hthi + (size_t)512 * 10 * 4 * 512;

    gemm_mfma<<<dim3((BB*NT)/128, 4), 256, 0, stream>>>(text,     Wt, xbuf, nullptr, nullptr, BB*NT, 768, 0, NT, 0);
    gemm_mfma<<<dim3((BB*NV)/128, 4), 256, 0, stream>>>(visual,   Wv, xbuf, nullptr, nullptr, BB*NV,  47, 0, NV, NT);
    gemm_mfma<<<dim3((BB*NA)/128, 4), 256, 0, stream>>>(acoustic, Wa, xbuf, nullptr, nullptr, BB*NA,  74, 0, NA, NT + NV);

    for (int l = 0; l < 2; l++) {
        const float* Wg_l = Wg + (size_t)l * NHEAD * HIDD * FD;
        gemm_mfma<<<dim3((BB*NN)/128, 4), 256, 0, stream>>>(xbuf, Wg_l, nullptr, Hthi, Htlo, BB*NN, HIDD, 1, NN, 0);
        attn_mfma<<<BB * NHEAD * 2, 512, 0, stream>>>(
            Hthi, Htlo, a_src + l * NHEAD * FD, a_dst + l * NHEAD * FD,
            adj, elog, xbuf, (l == 0) ? 1 : 0);
    }
}